// Round 4
// baseline (846.635 us; speedup 1.0000x reference)
//
#include <hip/hip_runtime.h>
#include <hip/hip_bf16.h>

typedef __hip_bfloat16 bf16;
typedef __attribute__((ext_vector_type(4))) _Float16 half4;   // 4 f16 = 2 VGPR MFMA operand
typedef __attribute__((ext_vector_type(2))) _Float16 half2v;
typedef __attribute__((ext_vector_type(4))) float f32x4;      // MFMA accumulator

#define NN 32
#define CC 96
#define TT 256
#define VV 25
#define SS 3
#define RR 12
#define OO 96
#define BCC 24
#define TV (TT*VV)     /* 6400 */
#define VV2 (VV*VV)    /* 625  */

__device__ __forceinline__ float b2f(bf16 v){ return __bfloat162float(v); }
__device__ __forceinline__ bf16  f2b(float v){ return __float2bfloat16(v); }
// bf16 bits -> fp32
__device__ __forceinline__ float u2f(unsigned short b){
    union{unsigned u; float f;} a; a.u = ((unsigned)b)<<16; return a.f;
}

// ---------------------------------------------------------------- K1: xm = mean_T(x)
__global__ __launch_bounds__(256) void k_mean(const float* __restrict__ x, float* __restrict__ xm)
{
    int idx = blockIdx.x*256 + threadIdx.x;          // (n*C + c)*V + v
    if (idx >= NN*CC*VV) return;
    int v  = idx % VV;
    int nc = idx / VV;
    const float* p = x + (size_t)nc*TV + v;
    float s = 0.f;
    for (int t=0;t<TT;t++) s += p[t*VV];
    xm[idx] = s * (1.0f/TT);
}

// ---------------------------------------------------------------- K2: A_at[n,s,o,u,v]
__global__ __launch_bounds__(256) void k_aat(
    const float* __restrict__ xm,
    const float* __restrict__ c1_w, const float* __restrict__ c1_b,
    const float* __restrict__ c2_w, const float* __restrict__ c2_b,
    const float* __restrict__ c4_w, const float* __restrict__ c4_b,
    const float* __restrict__ A3,  const float* __restrict__ A6, const float* __restrict__ spd,
    const float* __restrict__ alpha, const float* __restrict__ beta, const float* __restrict__ gamma,
    float* __restrict__ Aat)
{
    __shared__ float s_xm[CC*VV];
    __shared__ float s_x1[RR*VV], s_x2[RR*VV];
    __shared__ float s_R[RR*VV2];
    __shared__ float s_c4[OO*RR];
    __shared__ float s_A3[VV2], s_spd[VV2];
    int n = blockIdx.x / SS, s = blockIdx.x % SS;
    int tid = threadIdx.x;
    for (int i=tid;i<CC*VV;i+=256) s_xm[i] = xm[(size_t)n*CC*VV + i];
    for (int i=tid;i<OO*RR;i+=256) s_c4[i] = c4_w[s*OO*RR + i];
    for (int i=tid;i<VV2;i+=256){ s_A3[i]=A3[s*VV2+i]; s_spd[i]=spd[i]; }
    __syncthreads();
    for (int i=tid;i<RR*VV;i+=256){
        int r=i/VV, u=i-r*VV;
        float a1=0.f, a2=0.f;
        for (int c=0;c<CC;c++){
            float xv = s_xm[c*VV+u];
            a1 += c1_w[(s*RR+r)*CC+c]*xv;
            a2 += c2_w[(s*RR+r)*CC+c]*xv;
        }
        s_x1[i]=a1+c1_b[s*RR+r];
        s_x2[i]=a2+c2_b[s*RR+r];
    }
    __syncthreads();
    for (int i=tid;i<RR*VV2;i+=256){
        int r=i/VV2, uv=i-r*VV2, u=uv/VV, v=uv-u*VV;
        s_R[i] = tanhf(s_x1[r*VV+u]-s_x2[r*VV+v]);
    }
    __syncthreads();
    float al=alpha[0], be=beta[0], ga=gamma[0];
    float* op = Aat + ((size_t)n*SS+s)*OO*VV2;
    for (int i=tid;i<OO*VV2;i+=256){
        int o=i/VV2, uv=i-o*VV2;
        float m=0.f;
        #pragma unroll
        for (int r=0;r<RR;r++) m += s_c4[o*RR+r]*s_R[r*VV2+uv];
        m += c4_b[s*OO+o];
        op[i] = m*al + s_A3[uv] + A6[(o%6)*VV2+uv]*be + s_spd[uv]*ga;
    }
}

// ---------------------------------------------------------------- K3: fused GCN -> y (in d_out)
// ROUND-7 (= round-6 resubmit; infra failure, kernel never ran): stage-1 GEMM on the
// CDNA-classic v_mfma_f32_16x16x16_f16 (K=16, 4-elem fragments, layouts documented
// since gfx908):
//   A[m=lane&15][k=(lane>>4)*4+e], B[k=(lane>>4)*4+e][p=lane&15],
//   D[row=(lane>>4)*4+r][col=lane&15].
// NO XOR swizzle (padded rows instead), NO LDS aliasing (separate x3 buffer),
// NO hi/lo split (f16 RNE: stage-1 error est. ~0.04 after correlation amplification,
// + 0.0625 h1-bf16 floor < 0.196 threshold), NO XCD swizzle (block mapping identical
// to the passing round-3 baseline).
// Stage 2 (A . x3 + BN + residual) = round-3 known-good fp32 VALU code, unchanged.
#define XROW 20   /* halfs per padded row: 16 data + 4 pad -> 40 B, banks spread */
__global__ __launch_bounds__(256,2) void k_gcn(
    const float* __restrict__ x, const float* __restrict__ c3_w, const float* __restrict__ c3_b,
    const float* __restrict__ Aat, const float* __restrict__ gbn_s, const float* __restrict__ gbn_b,
    float* __restrict__ y)
{
    __shared__ __align__(16) _Float16 s_x[800*XROW];   // 32,000 B  [p][16ch + pad]
    __shared__ __align__(16) float    s_x3[12*896];    // 43,008 B
    __shared__ __align__(16) _Float16 s_w[6*16*16];    // 3,072 B   [ck][m][kk]
    __shared__ float s_cb[16];

    int bi  = blockIdx.x;
    int og  = bi % 24;
    int tcb = (bi/24) & 7;
    int n   = bi / 192;
    int t0  = tcb*32;
    int tid = threadIdx.x;

    // ---- stage W (f16) + bias; rows m=12..15 zero-padded
    for (int i=tid;i<16*96;i+=256){
        int m=i/96, c=i-m*96;
        float wf = 0.f;
        if (m<12){ int s=m>>2, op=m&3; wf = c3_w[(s*OO + og*4+op)*CC + c]; }
        s_w[((c>>4)*16+m)*16 + (c&15)] = (_Float16)wf;
    }
    if (tid<16){
        float b=0.f;
        if (tid<12){ int s=tid>>2, op=tid&3; b = c3_b[s*OO + og*4+op]; }
        s_cb[tid]=b;
    }

    int l  = tid & 63;
    int li = l & 15, q = l >> 4;
    int wv_id = tid >> 6;
    // 50 N-tiles of 16 p split across 4 waves: {13,13,13,11}
    int start = wv_id*13;
    int cnt   = (wv_id<3) ? 13 : 11;

    f32x4 acc[13];
    #pragma unroll
    for (int j=0;j<13;++j) acc[j] = (f32x4){0.f,0.f,0.f,0.f};

    size_t xb = (size_t)n*CC*TV + (size_t)t0*VV;
    for (int ck=0; ck<6; ++ck){
        __syncthreads();                            // prev chunk's MFMA reads done
        int c0 = ck*16;
        // stage 16 c-rows x 800 p as f16: 8 cpairs * 200 pq = 1600 tasks,
        // cpair = fast index so a wave's writes spread across banks (2-way, free).
        for (int it=0; it<7; ++it){
            int task = tid + it*256;
            if (task < 1600){
                int cpair = task & 7;
                int pq    = task >> 3;              // 0..199
                const float* r0 = x + xb + (size_t)(c0 + cpair*2)*TV + pq*4;
                float4 a = *(const float4*)r0;
                float4 b = *(const float4*)(r0 + TV);
                #pragma unroll
                for (int ii=0; ii<4; ++ii){
                    int p = pq*4 + ii;
                    half2v hv;
                    hv[0] = (_Float16)((&a.x)[ii]);
                    hv[1] = (_Float16)((&b.x)[ii]);
                    *(half2v*)&s_x[p*XROW + cpair*2] = hv;
                }
            }
        }
        __syncthreads();
        // A-frag: W[m=li][k = q*4+e] (4 contiguous f16 -> b64)
        half4 a4 = *(const half4*)(s_w + (ck*16+li)*16 + q*4);
        #pragma unroll
        for (int j=0;j<13;++j){
            if (j < cnt){
                // B-frag: x[ch = q*4+e][p = tile*16+li]
                half4 b4 = *(const half4*)(s_x + ((start+j)*16 + li)*XROW + q*4);
                acc[j] = __builtin_amdgcn_mfma_f32_16x16x16f16(a4, b4, acc[j], 0, 0, 0);
            }
        }
    }

    // ---- x3 (fp32) = acc + bias into separate LDS [12][32*28]
    // D layout: col(p) = li, row(m) = q*4 + r  -> quarter 3 holds only padded rows.
    if (q < 3){
        #pragma unroll
        for (int j=0;j<13;++j){
            if (j < cnt){
                int p = (start+j)*16 + li;
                int t = p/25, v = p - t*25;
                float* dst = s_x3 + (q*4)*896 + t*28 + v;
                #pragma unroll
                for (int r=0;r<4;++r)
                    dst[r*896] = acc[j][r] + s_cb[q*4+r];
            }
        }
    }
    __syncthreads();

    // ---- stage 2: y[t,u] = sum_{s,v} A[s,u,v]*x3[s,t,v]   (round-3 known-good code)
    int w  = wv_id;             // wave id = local o
    int u  = l & 31;
    int th = l >> 5;
    int o  = og*4 + w;
    int u_eff = (u<VV)?u:(VV-1);
    float areg[75];
    #pragma unroll
    for (int s=0;s<3;s++){
        const float* Ap = Aat + (((size_t)n*SS+s)*OO + o)*VV2 + (size_t)u_eff*VV;
        #pragma unroll
        for (int v=0;v<25;v++) areg[s*25+v] = Ap[v];
    }
    float gs = gbn_s[o], gb = gbn_b[o];
    for (int ti=0; ti<16; ti++){
        int tl = ti*2 + th;
        float a2 = 0.f;
        #pragma unroll
        for (int s=0;s<3;s++){
            const float* xr = &s_x3[(s*4+w)*896 + tl*28];
            #pragma unroll
            for (int vc=0; vc<6; vc++){
                float4 xv4 = *(const float4*)(xr + vc*4);
                a2 += xv4.x*areg[s*25+vc*4]   + xv4.y*areg[s*25+vc*4+1]
                    + xv4.z*areg[s*25+vc*4+2] + xv4.w*areg[s*25+vc*4+3];
            }
            a2 += xr[24]*areg[s*25+24];
        }
        if (u < VV){
            int t = t0 + tl;
            size_t oix = ((size_t)(n*OO+o)*TT + t)*VV + u;
            float yv = gs*a2 + gb + x[oix];
            y[oix] = yv>0.f?yv:0.f;
        }
    }
}

// ---------------------------------------------------------------- K4a: pointwise, branches 0..2 -> h1 (bf16)
__global__ __launch_bounds__(256,2) void k_pw_h(
    const float* __restrict__ yws, const float* __restrict__ pw_w, const float* __restrict__ pw_b,
    const float* __restrict__ pwbn_s, const float* __restrict__ pwbn_b,
    bf16* __restrict__ h1)
{
    __shared__ __align__(16) float s_w[OO*BCC];
    __shared__ float s_sc[BCC], s_sh[BCC];
    int b   = blockIdx.x/160;
    int rem = blockIdx.x - b*160;
    int n   = rem/5;
    int chunk = rem - (rem/5)*5;
    int pbase = chunk*256 + threadIdx.x;
    for (int i=threadIdx.x;i<OO*BCC;i+=256){
        int o=i/BCC, cp=i-o*BCC;
        s_w[i] = pw_w[(b*BCC+cp)*OO + o];
    }
    if (threadIdx.x<BCC){
        int cp=threadIdx.x;
        float sc = pwbn_s[b*BCC+cp];
        s_sc[cp]=sc;
        s_sh[cp]= sc*pw_b[b*BCC+cp] + pwbn_b[b*BCC+cp];
    }
    __syncthreads();
    float acc[5][BCC];
    #pragma unroll
    for (int j=0;j<5;j++)
        #pragma unroll
        for (int i=0;i<BCC;i++) acc[j][i]=0.f;
    const float* yp = yws + (size_t)n*OO*TV + pbase;
    for (int o=0;o<OO;o++){
        float wv[BCC];
        #pragma unroll
        for (int q=0;q<6;q++) *(float4*)&wv[q*4] = *(const float4*)&s_w[o*BCC + q*4];
        float yv[5];
        #pragma unroll
        for (int j=0;j<5;j++) yv[j] = yp[(size_t)o*TV + j*1280];
        #pragma unroll
        for (int j=0;j<5;j++)
            #pragma unroll
            for (int cp=0;cp<BCC;cp++) acc[j][cp] += wv[cp]*yv[j];
    }
    size_t hb = ((size_t)(b*NN+n)*BCC)*TV + pbase;
    #pragma unroll
    for (int j=0;j<5;j++)
        #pragma unroll
        for (int cp=0;cp<BCC;cp++){
            float h = s_sc[cp]*acc[j][cp] + s_sh[cp];
            h1[hb + (size_t)cp*TV + j*1280] = f2b(h>0.f?h:0.f);
        }
}

// ---------------------------------------------------------------- K4b: pointwise branch 3 -> out ch 72..95
__global__ __launch_bounds__(256,2) void k_pw3(
    float* yout, const float* __restrict__ pw_w, const float* __restrict__ pw_b,
    const float* __restrict__ pwbn_s, const float* __restrict__ pwbn_b,
    const float* __restrict__ x)
{
    __shared__ __align__(16) float s_w[OO*BCC];
    __shared__ float s_sc[BCC], s_sh[BCC];
    const int b = 3;
    int n   = blockIdx.x/5;
    int chunk = blockIdx.x - n*5;
    int pbase = chunk*256 + threadIdx.x;
    for (int i=threadIdx.x;i<OO*BCC;i+=256){
        int o=i/BCC, cp=i-o*BCC;
        s_w[i] = pw_w[(b*BCC+cp)*OO + o];
    }
    if (threadIdx.x<BCC){
        int cp=threadIdx.x;
        float sc = pwbn_s[b*BCC+cp];
        s_sc[cp]=sc;
        s_sh[cp]= sc*pw_b[b*BCC+cp] + pwbn_b[b*BCC+cp];
    }
    __syncthreads();
    float acc[5][BCC];
    #pragma unroll
    for (int j=0;j<5;j++)
        #pragma unroll
        for (int i=0;i<BCC;i++) acc[j][i]=0.f;
    const float* yp = yout + (size_t)n*OO*TV + pbase;
    for (int o=0;o<OO;o++){
        float wv[BCC];
        #pragma unroll
        for (int q=0;q<6;q++) *(float4*)&wv[q*4] = *(const float4*)&s_w[o*BCC + q*4];
        float yv[5];
        #pragma unroll
        for (int j=0;j<5;j++) yv[j] = yp[(size_t)o*TV + j*1280];
        #pragma unroll
        for (int j=0;j<5;j++)
            #pragma unroll
            for (int cp=0;cp<BCC;cp++) acc[j][cp] += wv[cp]*yv[j];
    }
    size_t ob = ((size_t)n*OO + 72)*TV + pbase;
    #pragma unroll
    for (int j=0;j<5;j++)
        #pragma unroll
        for (int cp=0;cp<BCC;cp++){
            float h = s_sc[cp]*acc[j][cp] + s_sh[cp];
            size_t ix = ob + (size_t)cp*TV + j*1280;
            float r = h + x[ix];
            yout[ix] = r>0.f?r:0.f;
        }
}

// ---------------------------------------------------------------- K5: temporal convs + maxpool -> out ch 0..71
template<int D>
__device__ __forceinline__ void tcn_conv(int n, int br, int t0, int t4, int v, int vv, bool act,
    const float* __restrict__ tc_w, const float* __restrict__ tc_b,
    const float* __restrict__ tcbn_s, const float* __restrict__ tcbn_b,
    const float* __restrict__ x, float* __restrict__ out, const unsigned short* s_h)
{
    const int W = 4 + 4*D;
    int tb = 4 + t4*4 - 2*D;
    for (int g=0; g<4; g++){
        float acc[6][4];
        #pragma unroll
        for (int cpi=0;cpi<6;cpi++)
            #pragma unroll
            for (int i=0;i<4;i++) acc[cpi][i]=0.f;
        for (int ci=0; ci<24; ci++){
            float win[W];
            #pragma unroll
            for (int j=0;j<W;j++) win[j] = u2f(s_h[(ci*40 + tb + j)*26 + vv]);
            #pragma unroll
            for (int cpi=0; cpi<6; cpi++){
                int cp = g*6+cpi;
                const float* wp = tc_w + ((br*BCC+cp)*BCC + ci)*5;   // uniform -> s_load
                float w0=wp[0],w1=wp[1],w2=wp[2],w3=wp[3],w4=wp[4];
                #pragma unroll
                for (int i=0;i<4;i++)
                    acc[cpi][i] += w0*win[i] + w1*win[i+D] + w2*win[i+2*D]
                                 + w3*win[i+3*D] + w4*win[i+4*D];
            }
        }
        if (act){
            #pragma unroll
            for (int cpi=0; cpi<6; cpi++){
                int ch = br*BCC + g*6+cpi;
                float tbias=tc_b[ch], ts=tcbn_s[ch], tb2=tcbn_b[ch];
                #pragma unroll
                for (int i=0;i<4;i++){
                    size_t oix = ((size_t)(n*OO+ch)*TT + (t0+t4*4+i))*VV + v;
                    float r = ts*(acc[cpi][i]+tbias) + tb2 + x[oix];
                    out[oix] = r>0.f?r:0.f;
                }
            }
        }
    }
}

__global__ __launch_bounds__(256,2) void k_tcn(
    const bf16* __restrict__ h1, const float* __restrict__ tc_w, const float* __restrict__ tc_b,
    const float* __restrict__ tcbn_s, const float* __restrict__ tcbn_b,
    const float* __restrict__ mpbn_s, const float* __restrict__ mpbn_b,
    const float* __restrict__ x, float* __restrict__ out)
{
    __shared__ unsigned short s_h[24*40*26];   // 49,920 B
    int bi  = blockIdx.x;
    int n   = bi / 24;
    int rem = bi % 24;
    int br  = rem >> 3;        // 0,1 = conv branches; 2 = maxpool
    int tcb = rem & 7;
    int t0  = tcb*32;
    int tid = threadIdx.x;

    const unsigned short* hb = (const unsigned short*)(h1 + ((size_t)(br*NN+n)*BCC)*TV);
    unsigned short padv = (br==2) ? (unsigned short)0xFF80 : (unsigned short)0;  // -inf / 0
    for (int ci=0; ci<24; ci++){
        const unsigned short* hc = hb + (size_t)ci*TV;
        #pragma unroll
        for (int j=0;j<5;j++){
            int idx = j*256 + tid;
            if (idx < 1040){
                int tt = idx/26, v = idx - tt*26;
                int gt = t0 - 4 + tt;
                unsigned short bits = padv;
                if (v<25 && gt>=0 && gt<TT) bits = hc[gt*VV+v];
                s_h[(ci*40+tt)*26 + v] = bits;
            }
        }
    }
    __syncthreads();

    int t4 = tid>>5, v = tid&31;
    bool act = v<25;
    int vv = act ? v : 24;

    if (br==0){
        tcn_conv<1>(n,br,t0,t4,v,vv,act,tc_w,tc_b,tcbn_s,tcbn_b,x,out,s_h);
    } else if (br==1){
        tcn_conv<2>(n,br,t0,t4,v,vv,act,tc_w,tc_b,tcbn_s,tcbn_b,x,out,s_h);
    } else {
        int tb = 4 + t4*4 - 1;
        for (int cp=0; cp<24; cp++){
            float win[6];
            #pragma unroll
            for (int j=0;j<6;j++) win[j] = u2f(s_h[(cp*40 + tb + j)*26 + vv]);
            float ms=mpbn_s[cp], mb=mpbn_b[cp];
            if (act){
                #pragma unroll
                for (int i=0;i<4;i++){
                    float m = fmaxf(fmaxf(win[i],win[i+1]),win[i+2]);
                    size_t oix = ((size_t)(n*OO+(48+cp))*TT + (t0+t4*4+i))*VV + v;
                    float r = ms*m + mb + x[oix];
                    out[oix] = r>0.f?r:0.f;
                }
            }
        }
    }
}

// ----------------------------------------------------------------
// Workspace (29,491,200 B): phase A: xm [0,307200) + Aat [307200, 23,347,200)
//                           phase B: h1 bf16 [0, 29,491,200) (aliases A; A dead after k_gcn)
// y lives in d_out (fp32), overwritten in place by k_pw3/k_tcn.
extern "C" void kernel_launch(void* const* d_in, const int* in_sizes, int n_in,
                              void* d_out, int out_size, void* d_ws, size_t ws_size,
                              hipStream_t stream)
{
    const float* x     = (const float*)d_in[0];
    const float* spd   = (const float*)d_in[1];
    const float* A3    = (const float*)d_in[2];
    const float* A6    = (const float*)d_in[3];
    const float* alpha = (const float*)d_in[4];
    const float* beta  = (const float*)d_in[5];
    const float* gamma = (const float*)d_in[6];
    const float* c1_w  = (const float*)d_in[7];
    const float* c1_b  = (const float*)d_in[8];
    const float* c2_w  = (const float*)d_in[9];
    const float* c2_b  = (const float*)d_in[10];
    const float* c4_w  = (const float*)d_in[11];
    const float* c4_b  = (const float*)d_in[12];
    const float* c3_w  = (const float*)d_in[13];
    const float* c3_b  = (const float*)d_in[14];
    const float* gbn_s = (const float*)d_in[15];
    const float* gbn_b = (const float*)d_in[16];
    const float* pw_w  = (const float*)d_in[17];
    const float* pw_b  = (const float*)d_in[18];
    const float* pwbn_s= (const float*)d_in[19];
    const float* pwbn_b= (const float*)d_in[20];
    const float* tc_w  = (const float*)d_in[21];
    const float* tc_b  = (const float*)d_in[22];
    const float* tcbn_s= (const float*)d_in[23];
    const float* tcbn_b= (const float*)d_in[24];
    const float* mpbn_s= (const float*)d_in[25];
    const float* mpbn_b= (const float*)d_in[26];
    float* out = (float*)d_out;

    char* ws = (char*)d_ws;
    float* xm  = (float*)(ws);
    float* Aat = (float*)(ws + 307200);
    bf16*  h1  = (bf16*)(ws);            // aliases xm/Aat (dead by then)

    k_mean<<<dim3(300), dim3(256), 0, stream>>>(x, xm);
    k_aat <<<dim3(96),  dim3(256), 0, stream>>>(xm, c1_w,c1_b,c2_w,c2_b,c4_w,c4_b,
                                                A3, A6, spd, alpha, beta, gamma, Aat);
    k_gcn <<<dim3(6144),dim3(256), 0, stream>>>(x, c3_w, c3_b, Aat, gbn_s, gbn_b, out);
    k_pw_h<<<dim3(480), dim3(256), 0, stream>>>(out, pw_w, pw_b, pwbn_s, pwbn_b, h1);
    k_pw3 <<<dim3(160), dim3(256), 0, stream>>>(out, pw_w, pw_b, pwbn_s, pwbn_b, x);
    k_tcn <<<dim3(768), dim3(256), 0, stream>>>(h1, tc_w, tc_b, tcbn_s, tcbn_b,
                                                mpbn_s, mpbn_b, x, out);
}

// Round 6
// 809.454 us; speedup vs baseline: 1.0459x; 1.0459x over previous
//
#include <hip/hip_runtime.h>
#include <hip/hip_bf16.h>

typedef __hip_bfloat16 bf16;
typedef __attribute__((ext_vector_type(4))) _Float16 half4;   // 4 f16 = 2 VGPR MFMA operand
typedef __attribute__((ext_vector_type(2))) _Float16 half2v;
typedef __attribute__((ext_vector_type(4))) float f32x4;      // MFMA accumulator

#define NN 32
#define CC 96
#define TT 256
#define VV 25
#define SS 3
#define RR 12
#define OO 96
#define BCC 24
#define TV (TT*VV)     /* 6400 */
#define VV2 (VV*VV)    /* 625  */

__device__ __forceinline__ float b2f(bf16 v){ return __bfloat162float(v); }
__device__ __forceinline__ bf16  f2b(float v){ return __float2bfloat16(v); }
// bf16 bits -> fp32
__device__ __forceinline__ float u2f(unsigned short b){
    union{unsigned u; float f;} a; a.u = ((unsigned)b)<<16; return a.f;
}

// ---------------------------------------------------------------- K1: xm = mean_T(x)
__global__ __launch_bounds__(256) void k_mean(const float* __restrict__ x, float* __restrict__ xm)
{
    int idx = blockIdx.x*256 + threadIdx.x;          // (n*C + c)*V + v
    if (idx >= NN*CC*VV) return;
    int v  = idx % VV;
    int nc = idx / VV;
    const float* p = x + (size_t)nc*TV + v;
    float s = 0.f;
    for (int t=0;t<TT;t++) s += p[t*VV];
    xm[idx] = s * (1.0f/TT);
}

// ---------------------------------------------------------------- K2: A_at[n,s,o,u,v]
__global__ __launch_bounds__(256) void k_aat(
    const float* __restrict__ xm,
    const float* __restrict__ c1_w, const float* __restrict__ c1_b,
    const float* __restrict__ c2_w, const float* __restrict__ c2_b,
    const float* __restrict__ c4_w, const float* __restrict__ c4_b,
    const float* __restrict__ A3,  const float* __restrict__ A6, const float* __restrict__ spd,
    const float* __restrict__ alpha, const float* __restrict__ beta, const float* __restrict__ gamma,
    float* __restrict__ Aat)
{
    __shared__ float s_xm[CC*VV];
    __shared__ float s_x1[RR*VV], s_x2[RR*VV];
    __shared__ float s_R[RR*VV2];
    __shared__ float s_c4[OO*RR];
    __shared__ float s_A3[VV2], s_spd[VV2];
    int n = blockIdx.x / SS, s = blockIdx.x % SS;
    int tid = threadIdx.x;
    for (int i=tid;i<CC*VV;i+=256) s_xm[i] = xm[(size_t)n*CC*VV + i];
    for (int i=tid;i<OO*RR;i+=256) s_c4[i] = c4_w[s*OO*RR + i];
    for (int i=tid;i<VV2;i+=256){ s_A3[i]=A3[s*VV2+i]; s_spd[i]=spd[i]; }
    __syncthreads();
    for (int i=tid;i<RR*VV;i+=256){
        int r=i/VV, u=i-r*VV;
        float a1=0.f, a2=0.f;
        for (int c=0;c<CC;c++){
            float xv = s_xm[c*VV+u];
            a1 += c1_w[(s*RR+r)*CC+c]*xv;
            a2 += c2_w[(s*RR+r)*CC+c]*xv;
        }
        s_x1[i]=a1+c1_b[s*RR+r];
        s_x2[i]=a2+c2_b[s*RR+r];
    }
    __syncthreads();
    for (int i=tid;i<RR*VV2;i+=256){
        int r=i/VV2, uv=i-r*VV2, u=uv/VV, v=uv-u*VV;
        s_R[i] = tanhf(s_x1[r*VV+u]-s_x2[r*VV+v]);
    }
    __syncthreads();
    float al=alpha[0], be=beta[0], ga=gamma[0];
    float* op = Aat + ((size_t)n*SS+s)*OO*VV2;
    for (int i=tid;i<OO*VV2;i+=256){
        int o=i/VV2, uv=i-o*VV2;
        float m=0.f;
        #pragma unroll
        for (int r=0;r<RR;r++) m += s_c4[o*RR+r]*s_R[r*VV2+uv];
        m += c4_b[s*OO+o];
        op[i] = m*al + s_A3[uv] + A6[(o%6)*VV2+uv]*be + s_spd[uv]*ga;
    }
}

// ---------------------------------------------------------------- K3: fused GCN -> y (in d_out)
// ROUND-9 (bisection of round-8 fail): BOTH stages on v_mfma_f32_16x16x16_f16,
// identical logic to round-8, with exactly three deltas:
//   (1) NO LDS aliasing  - s_x and s_x3h are separate named __shared__ arrays,
//       no reinterpret-casts (this is the factor correlated with all 3 failures);
//   (2) NO XCD swizzle   - bi = blockIdx.x (the other changed factor);
//   (3) x3 pad columns k=75..83 zero-initialized (stage-2 MFMA reads k=75..79;
//       previously uninitialized LDS - latent NaN poison).
// Stage-1 staging/MFMA structure byte-identical to the round-7 PASSING kernel.
#define XROW  20    /* halfs per padded x row: 16 data + 4 pad -> 40 B */
#define X3ROW 84    /* halfs per x3 row (k-dim padded 80->84) */
#define X3OP  (32*X3ROW)   /* 2688 halfs per op slice */
__global__ __launch_bounds__(256,2) void k_gcn(
    const float* __restrict__ x, const float* __restrict__ c3_w, const float* __restrict__ c3_b,
    const float* __restrict__ Aat, const float* __restrict__ gbn_s, const float* __restrict__ gbn_b,
    float* __restrict__ y)
{
    __shared__ __align__(16) _Float16 s_x[800*XROW];     // 32,000 B  [p][16ch + pad]
    __shared__ __align__(16) _Float16 s_x3h[4*X3OP];     // 21,504 B  [op][t][84: k=s*25+v]
    __shared__ __align__(16) _Float16 s_w[6*16*16];      // 3,072 B   [ck][m][kk]
    __shared__ float s_cb[16];

    int bi  = blockIdx.x;                   // NO swizzle this round
    int og  = bi % 24;
    int tcb = (bi/24) & 7;
    int n   = bi / 192;
    int t0  = tcb*32;
    int tid = threadIdx.x;

    // ---- zero x3 pad columns (k=75..83) so stage-2 MFMA pad reads are exactly 0
    for (int i=tid; i<4*32*9; i+=256){
        int op2 = i/288, r2 = i - op2*288;
        int t = r2/9, kk = 75 + (r2 - t*9);
        s_x3h[op2*X3OP + t*X3ROW + kk] = (_Float16)0.f;
    }

    // ---- stage W (f16) + bias; rows m=12..15 zero-padded
    for (int i=tid;i<16*96;i+=256){
        int m=i/96, c=i-m*96;
        float wf = 0.f;
        if (m<12){ int s=m>>2, op=m&3; wf = c3_w[(s*OO + og*4+op)*CC + c]; }
        s_w[((c>>4)*16+m)*16 + (c&15)] = (_Float16)wf;
    }
    if (tid<16){
        float b=0.f;
        if (tid<12){ int s=tid>>2, op=tid&3; b = c3_b[s*OO + og*4+op]; }
        s_cb[tid]=b;
    }

    int l  = tid & 63;
    int li = l & 15, q = l >> 4;
    int wv_id = tid >> 6;
    int o  = og*4 + wv_id;

    // ---- A-regs for stage 2 (global loads issued early; latency hides under stage 1)
    // A-frag element: lane(li,q), tile(mt,kc), e: A[u=mt*16+li][k=kc*16+q*4+e], k=(s,v)=s*25+v
    half4 areg[2][5];
    #pragma unroll
    for (int mt=0; mt<2; ++mt){
        int u = mt*16 + li;
        #pragma unroll
        for (int kc=0; kc<5; ++kc){
            half4 h;
            #pragma unroll
            for (int e=0; e<4; ++e){
                int k = kc*16 + q*4 + e;
                float av = 0.f;
                if (u < VV && k < 75){
                    int s = k/25, v = k - s*25;
                    av = Aat[(((size_t)n*SS+s)*OO + o)*VV2 + u*VV + v];
                }
                h[e] = (_Float16)av;
            }
            areg[mt][kc] = h;
        }
    }
    float gs = gbn_s[o], gb = gbn_b[o];

    // 50 N-tiles of 16 p split across 4 waves: {13,13,13,11}
    int start = wv_id*13;
    int cnt   = (wv_id<3) ? 13 : 11;

    f32x4 acc[13];
    #pragma unroll
    for (int j=0;j<13;++j) acc[j] = (f32x4){0.f,0.f,0.f,0.f};

    // ---- stage 1: x3 = W . x  (round-7 verified structure, unchanged)
    size_t xb = (size_t)n*CC*TV + (size_t)t0*VV;
    for (int ck=0; ck<6; ++ck){
        __syncthreads();                            // prev chunk's MFMA reads done
        int c0 = ck*16;
        for (int it=0; it<7; ++it){
            int task = tid + it*256;
            if (task < 1600){
                int cpair = task & 7;
                int pq    = task >> 3;              // 0..199
                const float* r0 = x + xb + (size_t)(c0 + cpair*2)*TV + pq*4;
                float4 a = *(const float4*)r0;
                float4 b = *(const float4*)(r0 + TV);
                #pragma unroll
                for (int ii=0; ii<4; ++ii){
                    int p = pq*4 + ii;
                    half2v hv;
                    hv[0] = (_Float16)((&a.x)[ii]);
                    hv[1] = (_Float16)((&b.x)[ii]);
                    *(half2v*)&s_x[p*XROW + cpair*2] = hv;
                }
            }
        }
        __syncthreads();
        half4 a4 = *(const half4*)(s_w + (ck*16+li)*16 + q*4);
        #pragma unroll
        for (int j=0;j<13;++j){
            if (j < cnt){
                half4 b4 = *(const half4*)(s_x + ((start+j)*16 + li)*XROW + q*4);
                acc[j] = __builtin_amdgcn_mfma_f32_16x16x16f16(a4, b4, acc[j], 0, 0, 0);
            }
        }
    }
    __syncthreads();

    // ---- x3 (f16) = acc + bias into separate LDS [op][t][84]
    // stage-1 D: col(p)=li, row(m)=q*4+r; m = s*4+op -> s=q, op=r (q==3 rows are pad)
    if (q < 3){
        #pragma unroll
        for (int j=0;j<13;++j){
            if (j < cnt){
                int p = (start+j)*16 + li;
                int t = p/25, v = p - t*25;
                int base = t*X3ROW + q*25 + v;      // k = s*25+v = q*25+v
                #pragma unroll
                for (int r=0;r<4;++r)
                    s_x3h[r*X3OP + base] = (_Float16)(acc[j][r] + s_cb[q*4+r]);
            }
        }
    }
    __syncthreads();

    // ---- stage 2: y[u,t] = sum_k A[u,k] * x3[k,t]  via 20 MFMAs per wave
    const _Float16* bb = s_x3h + wv_id*X3OP;
    f32x4 acc2[2][2];
    #pragma unroll
    for (int mt=0;mt<2;++mt)
        #pragma unroll
        for (int nt=0;nt<2;++nt) acc2[mt][nt] = (f32x4){0.f,0.f,0.f,0.f};
    #pragma unroll
    for (int kc=0;kc<5;++kc){
        #pragma unroll
        for (int nt=0;nt<2;++nt){
            // B-frag: x3[k=kc*16+q*4+e][t=nt*16+li]
            half4 b4 = *(const half4*)(bb + (nt*16+li)*X3ROW + kc*16 + q*4);
            #pragma unroll
            for (int mt=0;mt<2;++mt)
                acc2[mt][nt] = __builtin_amdgcn_mfma_f32_16x16x16f16(areg[mt][kc], b4, acc2[mt][nt], 0, 0, 0);
        }
    }
    // epilogue: BN + residual + relu; D: row=u (q*4+r within mt), col=t (li within nt)
    #pragma unroll
    for (int mt=0;mt<2;++mt){
        #pragma unroll
        for (int nt=0;nt<2;++nt){
            int t = nt*16 + li;
            #pragma unroll
            for (int r=0;r<4;++r){
                int u = mt*16 + q*4 + r;
                if (u < VV){
                    size_t oix = ((size_t)(n*OO+o)*TT + (t0+t))*VV + u;
                    float yv = gs*acc2[mt][nt][r] + gb + x[oix];
                    y[oix] = yv>0.f?yv:0.f;
                }
            }
        }
    }
}

// ---------------------------------------------------------------- K4a: pointwise, branches 0..2 -> h1 (bf16)
__global__ __launch_bounds__(256,2) void k_pw_h(
    const float* __restrict__ yws, const float* __restrict__ pw_w, const float* __restrict__ pw_b,
    const float* __restrict__ pwbn_s, const float* __restrict__ pwbn_b,
    bf16* __restrict__ h1)
{
    __shared__ __align__(16) float s_w[OO*BCC];
    __shared__ float s_sc[BCC], s_sh[BCC];
    int b   = blockIdx.x/160;
    int rem = blockIdx.x - b*160;
    int n   = rem/5;
    int chunk = rem - (rem/5)*5;
    int pbase = chunk*256 + threadIdx.x;
    for (int i=threadIdx.x;i<OO*BCC;i+=256){
        int o=i/BCC, cp=i-o*BCC;
        s_w[i] = pw_w[(b*BCC+cp)*OO + o];
    }
    if (threadIdx.x<BCC){
        int cp=threadIdx.x;
        float sc = pwbn_s[b*BCC+cp];
        s_sc[cp]=sc;
        s_sh[cp]= sc*pw_b[b*BCC+cp] + pwbn_b[b*BCC+cp];
    }
    __syncthreads();
    float acc[5][BCC];
    #pragma unroll
    for (int j=0;j<5;j++)
        #pragma unroll
        for (int i=0;i<BCC;i++) acc[j][i]=0.f;
    const float* yp = yws + (size_t)n*OO*TV + pbase;
    for (int o=0;o<OO;o++){
        float wv[BCC];
        #pragma unroll
        for (int q=0;q<6;q++) *(float4*)&wv[q*4] = *(const float4*)&s_w[o*BCC + q*4];
        float yv[5];
        #pragma unroll
        for (int j=0;j<5;j++) yv[j] = yp[(size_t)o*TV + j*1280];
        #pragma unroll
        for (int j=0;j<5;j++)
            #pragma unroll
            for (int cp=0;cp<BCC;cp++) acc[j][cp] += wv[cp]*yv[j];
    }
    size_t hb = ((size_t)(b*NN+n)*BCC)*TV + pbase;
    #pragma unroll
    for (int j=0;j<5;j++)
        #pragma unroll
        for (int cp=0;cp<BCC;cp++){
            float h = s_sc[cp]*acc[j][cp] + s_sh[cp];
            h1[hb + (size_t)cp*TV + j*1280] = f2b(h>0.f?h:0.f);
        }
}

// ---------------------------------------------------------------- K4b: pointwise branch 3 -> out ch 72..95
__global__ __launch_bounds__(256,2) void k_pw3(
    float* yout, const float* __restrict__ pw_w, const float* __restrict__ pw_b,
    const float* __restrict__ pwbn_s, const float* __restrict__ pwbn_b,
    const float* __restrict__ x)
{
    __shared__ __align__(16) float s_w[OO*BCC];
    __shared__ float s_sc[BCC], s_sh[BCC];
    const int b = 3;
    int n   = blockIdx.x/5;
    int chunk = blockIdx.x - n*5;
    int pbase = chunk*256 + threadIdx.x;
    for (int i=threadIdx.x;i<OO*BCC;i+=256){
        int o=i/BCC, cp=i-o*BCC;
        s_w[i] = pw_w[(b*BCC+cp)*OO + o];
    }
    if (threadIdx.x<BCC){
        int cp=threadIdx.x;
        float sc = pwbn_s[b*BCC+cp];
        s_sc[cp]=sc;
        s_sh[cp]= sc*pw_b[b*BCC+cp] + pwbn_b[b*BCC+cp];
    }
    __syncthreads();
    float acc[5][BCC];
    #pragma unroll
    for (int j=0;j<5;j++)
        #pragma unroll
        for (int i=0;i<BCC;i++) acc[j][i]=0.f;
    const float* yp = yout + (size_t)n*OO*TV + pbase;
    for (int o=0;o<OO;o++){
        float wv[BCC];
        #pragma unroll
        for (int q=0;q<6;q++) *(float4*)&wv[q*4] = *(const float4*)&s_w[o*BCC + q*4];
        float yv[5];
        #pragma unroll
        for (int j=0;j<5;j++) yv[j] = yp[(size_t)o*TV + j*1280];
        #pragma unroll
        for (int j=0;j<5;j++)
            #pragma unroll
            for (int cp=0;cp<BCC;cp++) acc[j][cp] += wv[cp]*yv[j];
    }
    size_t ob = ((size_t)n*OO + 72)*TV + pbase;
    #pragma unroll
    for (int j=0;j<5;j++)
        #pragma unroll
        for (int cp=0;cp<BCC;cp++){
            float h = s_sc[cp]*acc[j][cp] + s_sh[cp];
            size_t ix = ob + (size_t)cp*TV + j*1280;
            float r = h + x[ix];
            yout[ix] = r>0.f?r:0.f;
        }
}

// ---------------------------------------------------------------- K5: temporal convs + maxpool -> out ch 0..71
template<int D>
__device__ __forceinline__ void tcn_conv(int n, int br, int t0, int t4, int v, int vv, bool act,
    const float* __restrict__ tc_w, const float* __restrict__ tc_b,
    const float* __restrict__ tcbn_s, const float* __restrict__ tcbn_b,
    const float* __restrict__ x, float* __restrict__ out, const unsigned short* s_h)
{
    const int W = 4 + 4*D;
    int tb = 4 + t4*4 - 2*D;
    for (int g=0; g<4; g++){
        float acc[6][4];
        #pragma unroll
        for (int cpi=0;cpi<6;cpi++)
            #pragma unroll
            for (int i=0;i<4;i++) acc[cpi][i]=0.f;
        for (int ci=0; ci<24; ci++){
            float win[W];
            #pragma unroll
            for (int j=0;j<W;j++) win[j] = u2f(s_h[(ci*40 + tb + j)*26 + vv]);
            #pragma unroll
            for (int cpi=0; cpi<6; cpi++){
                int cp = g*6+cpi;
                const float* wp = tc_w + ((br*BCC+cp)*BCC + ci)*5;   // uniform -> s_load
                float w0=wp[0],w1=wp[1],w2=wp[2],w3=wp[3],w4=wp[4];
                #pragma unroll
                for (int i=0;i<4;i++)
                    acc[cpi][i] += w0*win[i] + w1*win[i+D] + w2*win[i+2*D]
                                 + w3*win[i+3*D] + w4*win[i+4*D];
            }
        }
        if (act){
            #pragma unroll
            for (int cpi=0; cpi<6; cpi++){
                int ch = br*BCC + g*6+cpi;
                float tbias=tc_b[ch], ts=tcbn_s[ch], tb2=tcbn_b[ch];
                #pragma unroll
                for (int i=0;i<4;i++){
                    size_t oix = ((size_t)(n*OO+ch)*TT + (t0+t4*4+i))*VV + v;
                    float r = ts*(acc[cpi][i]+tbias) + tb2 + x[oix];
                    out[oix] = r>0.f?r:0.f;
                }
            }
        }
    }
}

__global__ __launch_bounds__(256,2) void k_tcn(
    const bf16* __restrict__ h1, const float* __restrict__ tc_w, const float* __restrict__ tc_b,
    const float* __restrict__ tcbn_s, const float* __restrict__ tcbn_b,
    const float* __restrict__ mpbn_s, const float* __restrict__ mpbn_b,
    const float* __restrict__ x, float* __restrict__ out)
{
    __shared__ unsigned short s_h[24*40*26];   // 49,920 B
    int bi  = blockIdx.x;
    int n   = bi / 24;
    int rem = bi % 24;
    int br  = rem >> 3;        // 0,1 = conv branches; 2 = maxpool
    int tcb = rem & 7;
    int t0  = tcb*32;
    int tid = threadIdx.x;

    const unsigned short* hb = (const unsigned short*)(h1 + ((size_t)(br*NN+n)*BCC)*TV);
    unsigned short padv = (br==2) ? (unsigned short)0xFF80 : (unsigned short)0;  // -inf / 0
    for (int ci=0; ci<24; ci++){
        const unsigned short* hc = hb + (size_t)ci*TV;
        #pragma unroll
        for (int j=0;j<5;j++){
            int idx = j*256 + tid;
            if (idx < 1040){
                int tt = idx/26, v = idx - tt*26;
                int gt = t0 - 4 + tt;
                unsigned short bits = padv;
                if (v<25 && gt>=0 && gt<TT) bits = hc[gt*VV+v];
                s_h[(ci*40+tt)*26 + v] = bits;
            }
        }
    }
    __syncthreads();

    int t4 = tid>>5, v = tid&31;
    bool act = v<25;
    int vv = act ? v : 24;

    if (br==0){
        tcn_conv<1>(n,br,t0,t4,v,vv,act,tc_w,tc_b,tcbn_s,tcbn_b,x,out,s_h);
    } else if (br==1){
        tcn_conv<2>(n,br,t0,t4,v,vv,act,tc_w,tc_b,tcbn_s,tcbn_b,x,out,s_h);
    } else {
        int tb = 4 + t4*4 - 1;
        for (int cp=0; cp<24; cp++){
            float win[6];
            #pragma unroll
            for (int j=0;j<6;j++) win[j] = u2f(s_h[(cp*40 + tb + j)*26 + vv]);
            float ms=mpbn_s[cp], mb=mpbn_b[cp];
            if (act){
                #pragma unroll
                for (int i=0;i<4;i++){
                    float m = fmaxf(fmaxf(win[i],win[i+1]),win[i+2]);
                    size_t oix = ((size_t)(n*OO+(48+cp))*TT + (t0+t4*4+i))*VV + v;
                    float r = ms*m + mb + x[oix];
                    out[oix] = r>0.f?r:0.f;
                }
            }
        }
    }
}

// ----------------------------------------------------------------
// Workspace (29,491,200 B): phase A: xm [0,307200) + Aat [307200, 23,347,200)
//                           phase B: h1 bf16 [0, 29,491,200) (aliases A; A dead after k_gcn)
// y lives in d_out (fp32), overwritten in place by k_pw3/k_tcn.
extern "C" void kernel_launch(void* const* d_in, const int* in_sizes, int n_in,
                              void* d_out, int out_size, void* d_ws, size_t ws_size,
                              hipStream_t stream)
{
    const float* x     = (const float*)d_in[0];
    const float* spd   = (const float*)d_in[1];
    const float* A3    = (const float*)d_in[2];
    const float* A6    = (const float*)d_in[3];
    const float* alpha = (const float*)d_in[4];
    const float* beta  = (const float*)d_in[5];
    const float* gamma = (const float*)d_in[6];
    const float* c1_w  = (const float*)d_in[7];
    const float* c1_b  = (const float*)d_in[8];
    const float* c2_w  = (const float*)d_in[9];
    const float* c2_b  = (const float*)d_in[10];
    const float* c4_w  = (const float*)d_in[11];
    const float* c4_b  = (const float*)d_in[12];
    const float* c3_w  = (const float*)d_in[13];
    const float* c3_b  = (const float*)d_in[14];
    const float* gbn_s = (const float*)d_in[15];
    const float* gbn_b = (const float*)d_in[16];
    const float* pw_w  = (const float*)d_in[17];
    const float* pw_b  = (const float*)d_in[18];
    const float* pwbn_s= (const float*)d_in[19];
    const float* pwbn_b= (const float*)d_in[20];
    const float* tc_w  = (const float*)d_in[21];
    const float* tc_b  = (const float*)d_in[22];
    const float* tcbn_s= (const float*)d_in[23];
    const float* tcbn_b= (const float*)d_in[24];
    const float* mpbn_s= (const float*)d_in[25];
    const float* mpbn_b= (const float*)d_in[26];
    float* out = (float*)d_out;

    char* ws = (char*)d_ws;
    float* xm  = (float*)(ws);
    float* Aat = (float*)(ws + 307200);
    bf16*  h1  = (bf16*)(ws);            // aliases xm/Aat (dead by then)

    k_mean<<<dim3(300), dim3(256), 0, stream>>>(x, xm);
    k_aat <<<dim3(96),  dim3(256), 0, stream>>>(xm, c1_w,c1_b,c2_w,c2_b,c4_w,c4_b,
                                                A3, A6, spd, alpha, beta, gamma, Aat);
    k_gcn <<<dim3(6144),dim3(256), 0, stream>>>(x, c3_w, c3_b, Aat, gbn_s, gbn_b, out);
    k_pw_h<<<dim3(480), dim3(256), 0, stream>>>(out, pw_w, pw_b, pwbn_s, pwbn_b, h1);
    k_pw3 <<<dim3(160), dim3(256), 0, stream>>>(out, pw_w, pw_b, pwbn_s, pwbn_b, x);
    k_tcn <<<dim3(768), dim3(256), 0, stream>>>(h1, tc_w, tc_b, tcbn_s, tcbn_b,
                                                mpbn_s, mpbn_b, x, out);
}

// Round 7
// 684.515 us; speedup vs baseline: 1.2368x; 1.1825x over previous
//
#include <hip/hip_runtime.h>
#include <hip/hip_bf16.h>

typedef __hip_bfloat16 bf16;
typedef __attribute__((ext_vector_type(4))) _Float16 half4;   // 4 f16 = 2 VGPR MFMA operand
typedef __attribute__((ext_vector_type(2))) _Float16 half2v;
typedef __attribute__((ext_vector_type(4))) float f32x4;      // MFMA accumulator

#define NN 32
#define CC 96
#define TT 256
#define VV 25
#define SS 3
#define RR 12
#define OO 96
#define BCC 24
#define TV (TT*VV)     /* 6400 */
#define VV2 (VV*VV)    /* 625  */

__device__ __forceinline__ float b2f(bf16 v){ return __bfloat162float(v); }
__device__ __forceinline__ bf16  f2b(float v){ return __float2bfloat16(v); }
// bf16 bits -> fp32
__device__ __forceinline__ float u2f(unsigned short b){
    union{unsigned u; float f;} a; a.u = ((unsigned)b)<<16; return a.f;
}

// ---------------------------------------------------------------- K1: xm = mean_T(x)
__global__ __launch_bounds__(256) void k_mean(const float* __restrict__ x, float* __restrict__ xm)
{
    int idx = blockIdx.x*256 + threadIdx.x;          // (n*C + c)*V + v
    if (idx >= NN*CC*VV) return;
    int v  = idx % VV;
    int nc = idx / VV;
    const float* p = x + (size_t)nc*TV + v;
    float s = 0.f;
    for (int t=0;t<TT;t++) s += p[t*VV];
    xm[idx] = s * (1.0f/TT);
}

// ---------------------------------------------------------------- K2: A_at[n,s,o,u,v]
__global__ __launch_bounds__(256) void k_aat(
    const float* __restrict__ xm,
    const float* __restrict__ c1_w, const float* __restrict__ c1_b,
    const float* __restrict__ c2_w, const float* __restrict__ c2_b,
    const float* __restrict__ c4_w, const float* __restrict__ c4_b,
    const float* __restrict__ A3,  const float* __restrict__ A6, const float* __restrict__ spd,
    const float* __restrict__ alpha, const float* __restrict__ beta, const float* __restrict__ gamma,
    float* __restrict__ Aat)
{
    __shared__ float s_xm[CC*VV];
    __shared__ float s_x1[RR*VV], s_x2[RR*VV];
    __shared__ float s_R[RR*VV2];
    __shared__ float s_c4[OO*RR];
    __shared__ float s_A3[VV2], s_spd[VV2];
    int n = blockIdx.x / SS, s = blockIdx.x % SS;
    int tid = threadIdx.x;
    for (int i=tid;i<CC*VV;i+=256) s_xm[i] = xm[(size_t)n*CC*VV + i];
    for (int i=tid;i<OO*RR;i+=256) s_c4[i] = c4_w[s*OO*RR + i];
    for (int i=tid;i<VV2;i+=256){ s_A3[i]=A3[s*VV2+i]; s_spd[i]=spd[i]; }
    __syncthreads();
    for (int i=tid;i<RR*VV;i+=256){
        int r=i/VV, u=i-r*VV;
        float a1=0.f, a2=0.f;
        for (int c=0;c<CC;c++){
            float xv = s_xm[c*VV+u];
            a1 += c1_w[(s*RR+r)*CC+c]*xv;
            a2 += c2_w[(s*RR+r)*CC+c]*xv;
        }
        s_x1[i]=a1+c1_b[s*RR+r];
        s_x2[i]=a2+c2_b[s*RR+r];
    }
    __syncthreads();
    for (int i=tid;i<RR*VV2;i+=256){
        int r=i/VV2, uv=i-r*VV2, u=uv/VV, v=uv-u*VV;
        s_R[i] = tanhf(s_x1[r*VV+u]-s_x2[r*VV+v]);
    }
    __syncthreads();
    float al=alpha[0], be=beta[0], ga=gamma[0];
    float* op = Aat + ((size_t)n*SS+s)*OO*VV2;
    for (int i=tid;i<OO*VV2;i+=256){
        int o=i/VV2, uv=i-o*VV2;
        float m=0.f;
        #pragma unroll
        for (int r=0;r<RR;r++) m += s_c4[o*RR+r]*s_R[r*VV2+uv];
        m += c4_b[s*OO+o];
        op[i] = m*al + s_A3[uv] + A6[(o%6)*VV2+uv]*be + s_spd[uv]*ga;
    }
}

// ---------------------------------------------------------------- K3: fused GCN -> y (in d_out)
// ROUND-10: same verified MFMA math as round-9 (PASS), staging DELETED.
//   Stage-1 B-frags load DIRECTLY global->reg: x[ch][p] with lanes li=0..15 reading
//   consecutive p (64B coalesced segments); 4 dword loads w/ imm offsets per frag.
//   W A-frags + bias also direct from global (lane-predicated, contiguous).
//   Removes s_x (32KB), s_w, and 13 of 14 barriers. LDS 56.8KB -> 21.5KB -> 4 blocks/CU.
// Retained from round-9 (the passing config): NO LDS aliasing (s_x3h separate named
// array), NO XCD swizzle, x3 pad columns zero-initialized.
// Stage-2 (20 MFMAs + epilogue) byte-identical to round-9.
#define X3ROW 84    /* halfs per x3 row (k-dim padded 80->84) */
#define X3OP  (32*X3ROW)   /* 2688 halfs per op slice */
__global__ __launch_bounds__(256,4) void k_gcn(
    const float* __restrict__ x, const float* __restrict__ c3_w, const float* __restrict__ c3_b,
    const float* __restrict__ Aat, const float* __restrict__ gbn_s, const float* __restrict__ gbn_b,
    float* __restrict__ y)
{
    __shared__ __align__(16) _Float16 s_x3h[4*X3OP];     // 21,504 B  [op][t][84: k=s*25+v]

    int bi  = blockIdx.x;                   // NO swizzle (round-9 passing config)
    int og  = bi % 24;
    int tcb = (bi/24) & 7;
    int n   = bi / 192;
    int t0  = tcb*32;
    int tid = threadIdx.x;

    // ---- zero x3 pad columns (k=75..83) so stage-2 MFMA pad reads are exactly 0
    for (int i=tid; i<4*32*9; i+=256){
        int op2 = i/288, r2 = i - op2*288;
        int t = r2/9, kk = 75 + (r2 - t*9);
        s_x3h[op2*X3OP + t*X3ROW + kk] = (_Float16)0.f;
    }

    int l  = tid & 63;
    int li = l & 15, q = l >> 4;
    int wv_id = tid >> 6;
    int o  = og*4 + wv_id;

    // ---- A-regs for stage 2 (global loads issued early; latency hides under stage 1)
    // A-frag element: lane(li,q), tile(mt,kc), e: A[u=mt*16+li][k=kc*16+q*4+e], k=(s,v)=s*25+v
    half4 areg[2][5];
    #pragma unroll
    for (int mt=0; mt<2; ++mt){
        int u = mt*16 + li;
        #pragma unroll
        for (int kc=0; kc<5; ++kc){
            half4 h;
            #pragma unroll
            for (int e=0; e<4; ++e){
                int k = kc*16 + q*4 + e;
                float av = 0.f;
                if (u < VV && k < 75){
                    int s = k/25, v = k - s*25;
                    av = Aat[(((size_t)n*SS+s)*OO + o)*VV2 + u*VV + v];
                }
                h[e] = (_Float16)av;
            }
            areg[mt][kc] = h;
        }
    }
    float gs = gbn_s[o], gb = gbn_b[o];

    // 50 N-tiles of 16 p split across 4 waves: {13,13,13,11}
    int start = wv_id*13;
    int cnt   = (wv_id<3) ? 13 : 11;

    f32x4 acc[13];
    #pragma unroll
    for (int j=0;j<13;++j) acc[j] = (f32x4){0.f,0.f,0.f,0.f};

    // ---- stage 1: x3 = W . x ; B-frags DIRECT from global (no LDS staging)
    // lane(li,q): A = W[m=li][c=ck*16+q*4+e], B = x[c=ck*16+q*4+e][p=(start+j)*16+li]
    size_t xb = (size_t)n*CC*TV + (size_t)t0*VV;
    bool wok = (li < 12);
    int  wrow = wok ? ((li>>2)*OO + og*4 + (li&3)) : 0;
    const float* wp  = c3_w + (size_t)wrow*CC + q*4;
    const float* xpb = x + xb + (size_t)(q*4)*TV + start*16 + li;

    for (int ck=0; ck<6; ++ck){
        float4 wv4 = *(const float4*)(wp + ck*16);
        half4 a4;
        a4[0] = (_Float16)(wok ? wv4.x : 0.f);
        a4[1] = (_Float16)(wok ? wv4.y : 0.f);
        a4[2] = (_Float16)(wok ? wv4.z : 0.f);
        a4[3] = (_Float16)(wok ? wv4.w : 0.f);
        const float* xc0 = xpb + (size_t)(ck*16)*TV;
        const float* xc1 = xc0 + TV;
        const float* xc2 = xc1 + TV;
        const float* xc3 = xc2 + TV;
        #pragma unroll
        for (int j=0;j<13;++j){
            if (j < cnt){
                half4 b4;
                b4[0] = (_Float16)xc0[j*16];
                b4[1] = (_Float16)xc1[j*16];
                b4[2] = (_Float16)xc2[j*16];
                b4[3] = (_Float16)xc3[j*16];
                acc[j] = __builtin_amdgcn_mfma_f32_16x16x16f16(a4, b4, acc[j], 0, 0, 0);
            }
        }
    }

    // ---- x3 (f16) = acc + bias into LDS [op][t][84]
    // stage-1 D: col(p)=li, row(m)=q*4+r; m = s*4+op -> s=q, op=r (q==3 rows are pad)
    int qq = (q<3) ? q : 0;
    float4 cb4 = *(const float4*)(c3_b + qq*OO + og*4);   // bias[r] = c3_b[q*OO+og*4+r]
    if (q < 3){
        #pragma unroll
        for (int j=0;j<13;++j){
            if (j < cnt){
                int p = (start+j)*16 + li;
                int t = p/25, v = p - t*25;
                int base = t*X3ROW + q*25 + v;      // k = s*25+v = q*25+v
                s_x3h[0*X3OP + base] = (_Float16)(acc[j][0] + cb4.x);
                s_x3h[1*X3OP + base] = (_Float16)(acc[j][1] + cb4.y);
                s_x3h[2*X3OP + base] = (_Float16)(acc[j][2] + cb4.z);
                s_x3h[3*X3OP + base] = (_Float16)(acc[j][3] + cb4.w);
            }
        }
    }
    __syncthreads();                                // the ONLY barrier

    // ---- stage 2: y[u,t] = sum_k A[u,k] * x3[k,t]  via 20 MFMAs per wave
    const _Float16* bb = s_x3h + wv_id*X3OP;
    f32x4 acc2[2][2];
    #pragma unroll
    for (int mt=0;mt<2;++mt)
        #pragma unroll
        for (int nt=0;nt<2;++nt) acc2[mt][nt] = (f32x4){0.f,0.f,0.f,0.f};
    #pragma unroll
    for (int kc=0;kc<5;++kc){
        #pragma unroll
        for (int nt=0;nt<2;++nt){
            // B-frag: x3[k=kc*16+q*4+e][t=nt*16+li]
            half4 b4 = *(const half4*)(bb + (nt*16+li)*X3ROW + kc*16 + q*4);
            #pragma unroll
            for (int mt=0;mt<2;++mt)
                acc2[mt][nt] = __builtin_amdgcn_mfma_f32_16x16x16f16(areg[mt][kc], b4, acc2[mt][nt], 0, 0, 0);
        }
    }
    // epilogue: BN + residual + relu; D: row=u (q*4+r within mt), col=t (li within nt)
    #pragma unroll
    for (int mt=0;mt<2;++mt){
        #pragma unroll
        for (int nt=0;nt<2;++nt){
            int t = nt*16 + li;
            #pragma unroll
            for (int r=0;r<4;++r){
                int u = mt*16 + q*4 + r;
                if (u < VV){
                    size_t oix = ((size_t)(n*OO+o)*TT + (t0+t))*VV + u;
                    float yv = gs*acc2[mt][nt][r] + gb + x[oix];
                    y[oix] = yv>0.f?yv:0.f;
                }
            }
        }
    }
}

// ---------------------------------------------------------------- K4a: pointwise, branches 0..2 -> h1 (bf16)
__global__ __launch_bounds__(256,2) void k_pw_h(
    const float* __restrict__ yws, const float* __restrict__ pw_w, const float* __restrict__ pw_b,
    const float* __restrict__ pwbn_s, const float* __restrict__ pwbn_b,
    bf16* __restrict__ h1)
{
    __shared__ __align__(16) float s_w[OO*BCC];
    __shared__ float s_sc[BCC], s_sh[BCC];
    int b   = blockIdx.x/160;
    int rem = blockIdx.x - b*160;
    int n   = rem/5;
    int chunk = rem - (rem/5)*5;
    int pbase = chunk*256 + threadIdx.x;
    for (int i=threadIdx.x;i<OO*BCC;i+=256){
        int o=i/BCC, cp=i-o*BCC;
        s_w[i] = pw_w[(b*BCC+cp)*OO + o];
    }
    if (threadIdx.x<BCC){
        int cp=threadIdx.x;
        float sc = pwbn_s[b*BCC+cp];
        s_sc[cp]=sc;
        s_sh[cp]= sc*pw_b[b*BCC+cp] + pwbn_b[b*BCC+cp];
    }
    __syncthreads();
    float acc[5][BCC];
    #pragma unroll
    for (int j=0;j<5;j++)
        #pragma unroll
        for (int i=0;i<BCC;i++) acc[j][i]=0.f;
    const float* yp = yws + (size_t)n*OO*TV + pbase;
    for (int o=0;o<OO;o++){
        float wv[BCC];
        #pragma unroll
        for (int q=0;q<6;q++) *(float4*)&wv[q*4] = *(const float4*)&s_w[o*BCC + q*4];
        float yv[5];
        #pragma unroll
        for (int j=0;j<5;j++) yv[j] = yp[(size_t)o*TV + j*1280];
        #pragma unroll
        for (int j=0;j<5;j++)
            #pragma unroll
            for (int cp=0;cp<BCC;cp++) acc[j][cp] += wv[cp]*yv[j];
    }
    size_t hb = ((size_t)(b*NN+n)*BCC)*TV + pbase;
    #pragma unroll
    for (int j=0;j<5;j++)
        #pragma unroll
        for (int cp=0;cp<BCC;cp++){
            float h = s_sc[cp]*acc[j][cp] + s_sh[cp];
            h1[hb + (size_t)cp*TV + j*1280] = f2b(h>0.f?h:0.f);
        }
}

// ---------------------------------------------------------------- K4b: pointwise branch 3 -> out ch 72..95
__global__ __launch_bounds__(256,2) void k_pw3(
    float* yout, const float* __restrict__ pw_w, const float* __restrict__ pw_b,
    const float* __restrict__ pwbn_s, const float* __restrict__ pwbn_b,
    const float* __restrict__ x)
{
    __shared__ __align__(16) float s_w[OO*BCC];
    __shared__ float s_sc[BCC], s_sh[BCC];
    const int b = 3;
    int n   = blockIdx.x/5;
    int chunk = blockIdx.x - n*5;
    int pbase = chunk*256 + threadIdx.x;
    for (int i=threadIdx.x;i<OO*BCC;i+=256){
        int o=i/BCC, cp=i-o*BCC;
        s_w[i] = pw_w[(b*BCC+cp)*OO + o];
    }
    if (threadIdx.x<BCC){
        int cp=threadIdx.x;
        float sc = pwbn_s[b*BCC+cp];
        s_sc[cp]=sc;
        s_sh[cp]= sc*pw_b[b*BCC+cp] + pwbn_b[b*BCC+cp];
    }
    __syncthreads();
    float acc[5][BCC];
    #pragma unroll
    for (int j=0;j<5;j++)
        #pragma unroll
        for (int i=0;i<BCC;i++) acc[j][i]=0.f;
    const float* yp = yout + (size_t)n*OO*TV + pbase;
    for (int o=0;o<OO;o++){
        float wv[BCC];
        #pragma unroll
        for (int q=0;q<6;q++) *(float4*)&wv[q*4] = *(const float4*)&s_w[o*BCC + q*4];
        float yv[5];
        #pragma unroll
        for (int j=0;j<5;j++) yv[j] = yp[(size_t)o*TV + j*1280];
        #pragma unroll
        for (int j=0;j<5;j++)
            #pragma unroll
            for (int cp=0;cp<BCC;cp++) acc[j][cp] += wv[cp]*yv[j];
    }
    size_t ob = ((size_t)n*OO + 72)*TV + pbase;
    #pragma unroll
    for (int j=0;j<5;j++)
        #pragma unroll
        for (int cp=0;cp<BCC;cp++){
            float h = s_sc[cp]*acc[j][cp] + s_sh[cp];
            size_t ix = ob + (size_t)cp*TV + j*1280;
            float r = h + x[ix];
            yout[ix] = r>0.f?r:0.f;
        }
}

// ---------------------------------------------------------------- K5: temporal convs + maxpool -> out ch 0..71
template<int D>
__device__ __forceinline__ void tcn_conv(int n, int br, int t0, int t4, int v, int vv, bool act,
    const float* __restrict__ tc_w, const float* __restrict__ tc_b,
    const float* __restrict__ tcbn_s, const float* __restrict__ tcbn_b,
    const float* __restrict__ x, float* __restrict__ out, const unsigned short* s_h)
{
    const int W = 4 + 4*D;
    int tb = 4 + t4*4 - 2*D;
    for (int g=0; g<4; g++){
        float acc[6][4];
        #pragma unroll
        for (int cpi=0;cpi<6;cpi++)
            #pragma unroll
            for (int i=0;i<4;i++) acc[cpi][i]=0.f;
        for (int ci=0; ci<24; ci++){
            float win[W];
            #pragma unroll
            for (int j=0;j<W;j++) win[j] = u2f(s_h[(ci*40 + tb + j)*26 + vv]);
            #pragma unroll
            for (int cpi=0; cpi<6; cpi++){
                int cp = g*6+cpi;
                const float* wp = tc_w + ((br*BCC+cp)*BCC + ci)*5;   // uniform -> s_load
                float w0=wp[0],w1=wp[1],w2=wp[2],w3=wp[3],w4=wp[4];
                #pragma unroll
                for (int i=0;i<4;i++)
                    acc[cpi][i] += w0*win[i] + w1*win[i+D] + w2*win[i+2*D]
                                 + w3*win[i+3*D] + w4*win[i+4*D];
            }
        }
        if (act){
            #pragma unroll
            for (int cpi=0; cpi<6; cpi++){
                int ch = br*BCC + g*6+cpi;
                float tbias=tc_b[ch], ts=tcbn_s[ch], tb2=tcbn_b[ch];
                #pragma unroll
                for (int i=0;i<4;i++){
                    size_t oix = ((size_t)(n*OO+ch)*TT + (t0+t4*4+i))*VV + v;
                    float r = ts*(acc[cpi][i]+tbias) + tb2 + x[oix];
                    out[oix] = r>0.f?r:0.f;
                }
            }
        }
    }
}

__global__ __launch_bounds__(256,2) void k_tcn(
    const bf16* __restrict__ h1, const float* __restrict__ tc_w, const float* __restrict__ tc_b,
    const float* __restrict__ tcbn_s, const float* __restrict__ tcbn_b,
    const float* __restrict__ mpbn_s, const float* __restrict__ mpbn_b,
    const float* __restrict__ x, float* __restrict__ out)
{
    __shared__ unsigned short s_h[24*40*26];   // 49,920 B
    int bi  = blockIdx.x;
    int n   = bi / 24;
    int rem = bi % 24;
    int br  = rem >> 3;        // 0,1 = conv branches; 2 = maxpool
    int tcb = rem & 7;
    int t0  = tcb*32;
    int tid = threadIdx.x;

    const unsigned short* hb = (const unsigned short*)(h1 + ((size_t)(br*NN+n)*BCC)*TV);
    unsigned short padv = (br==2) ? (unsigned short)0xFF80 : (unsigned short)0;  // -inf / 0
    for (int ci=0; ci<24; ci++){
        const unsigned short* hc = hb + (size_t)ci*TV;
        #pragma unroll
        for (int j=0;j<5;j++){
            int idx = j*256 + tid;
            if (idx < 1040){
                int tt = idx/26, v = idx - tt*26;
                int gt = t0 - 4 + tt;
                unsigned short bits = padv;
                if (v<25 && gt>=0 && gt<TT) bits = hc[gt*VV+v];
                s_h[(ci*40+tt)*26 + v] = bits;
            }
        }
    }
    __syncthreads();

    int t4 = tid>>5, v = tid&31;
    bool act = v<25;
    int vv = act ? v : 24;

    if (br==0){
        tcn_conv<1>(n,br,t0,t4,v,vv,act,tc_w,tc_b,tcbn_s,tcbn_b,x,out,s_h);
    } else if (br==1){
        tcn_conv<2>(n,br,t0,t4,v,vv,act,tc_w,tc_b,tcbn_s,tcbn_b,x,out,s_h);
    } else {
        int tb = 4 + t4*4 - 1;
        for (int cp=0; cp<24; cp++){
            float win[6];
            #pragma unroll
            for (int j=0;j<6;j++) win[j] = u2f(s_h[(cp*40 + tb + j)*26 + vv]);
            float ms=mpbn_s[cp], mb=mpbn_b[cp];
            if (act){
                #pragma unroll
                for (int i=0;i<4;i++){
                    float m = fmaxf(fmaxf(win[i],win[i+1]),win[i+2]);
                    size_t oix = ((size_t)(n*OO+(48+cp))*TT + (t0+t4*4+i))*VV + v;
                    float r = ms*m + mb + x[oix];
                    out[oix] = r>0.f?r:0.f;
                }
            }
        }
    }
}

// ----------------------------------------------------------------
// Workspace (29,491,200 B): phase A: xm [0,307200) + Aat [307200, 23,347,200)
//                           phase B: h1 bf16 [0, 29,491,200) (aliases A; A dead after k_gcn)
// y lives in d_out (fp32), overwritten in place by k_pw3/k_tcn.
extern "C" void kernel_launch(void* const* d_in, const int* in_sizes, int n_in,
                              void* d_out, int out_size, void* d_ws, size_t ws_size,
                              hipStream_t stream)
{
    const float* x     = (const float*)d_in[0];
    const float* spd   = (const float*)d_in[1];
    const float* A3    = (const float*)d_in[2];
    const float* A6    = (const float*)d_in[3];
    const float* alpha = (const float*)d_in[4];
    const float* beta  = (const float*)d_in[5];
    const float* gamma = (const float*)d_in[6];
    const float* c1_w  = (const float*)d_in[7];
    const float* c1_b  = (const float*)d_in[8];
    const float* c2_w  = (const float*)d_in[9];
    const float* c2_b  = (const float*)d_in[10];
    const float* c4_w  = (const float*)d_in[11];
    const float* c4_b  = (const float*)d_in[12];
    const float* c3_w  = (const float*)d_in[13];
    const float* c3_b  = (const float*)d_in[14];
    const float* gbn_s = (const float*)d_in[15];
    const float* gbn_b = (const float*)d_in[16];
    const float* pw_w  = (const float*)d_in[17];
    const float* pw_b  = (const float*)d_in[18];
    const float* pwbn_s= (const float*)d_in[19];
    const float* pwbn_b= (const float*)d_in[20];
    const float* tc_w  = (const float*)d_in[21];
    const float* tc_b  = (const float*)d_in[22];
    const float* tcbn_s= (const float*)d_in[23];
    const float* tcbn_b= (const float*)d_in[24];
    const float* mpbn_s= (const float*)d_in[25];
    const float* mpbn_b= (const float*)d_in[26];
    float* out = (float*)d_out;

    char* ws = (char*)d_ws;
    float* xm  = (float*)(ws);
    float* Aat = (float*)(ws + 307200);
    bf16*  h1  = (bf16*)(ws);            // aliases xm/Aat (dead by then)

    k_mean<<<dim3(300), dim3(256), 0, stream>>>(x, xm);
    k_aat <<<dim3(96),  dim3(256), 0, stream>>>(xm, c1_w,c1_b,c2_w,c2_b,c4_w,c4_b,
                                                A3, A6, spd, alpha, beta, gamma, Aat);
    k_gcn <<<dim3(6144),dim3(256), 0, stream>>>(x, c3_w, c3_b, Aat, gbn_s, gbn_b, out);
    k_pw_h<<<dim3(480), dim3(256), 0, stream>>>(out, pw_w, pw_b, pwbn_s, pwbn_b, h1);
    k_pw3 <<<dim3(160), dim3(256), 0, stream>>>(out, pw_w, pw_b, pwbn_s, pwbn_b, x);
    k_tcn <<<dim3(768), dim3(256), 0, stream>>>(h1, tc_w, tc_b, tcbn_s, tcbn_b,
                                                mpbn_s, mpbn_b, x, out);
}